// Round 12
// baseline (197.056 us; speedup 1.0000x reference)
//
#include <hip/hip_runtime.h>
#include <hip/hip_bf16.h>

typedef __attribute__((ext_vector_type(8))) short bf16x8;
typedef __attribute__((ext_vector_type(4))) float f32x4;

#define DI __device__ __forceinline__

#if __has_builtin(__builtin_amdgcn_exp2f)
#define EXP2(x) __builtin_amdgcn_exp2f(x)
#else
#define EXP2(x) exp2f(x)
#endif

DI short f2bf(float f) {
  __hip_bfloat16 b = __float2bfloat16(f);
  return __builtin_bit_cast(short, b);
}

DI void g2l16(const void* g, void* l) {
  __builtin_amdgcn_global_load_lds(
      (const __attribute__((address_space(1))) unsigned int*)g,
      (__attribute__((address_space(3))) unsigned int*)l, 16, 0, 0);
}

DI f32x4 mfma16(bf16x8 a, bf16x8 b, f32x4 c) {
  return __builtin_amdgcn_mfma_f32_16x16x32_bf16(a, b, c, 0, 0, 0);
}

// ---------------- f32 -> bf16 cast (vectorized) ----------------
__global__ void k_cvt(const float* __restrict__ in, short* __restrict__ out, int n4) {
  int i = blockIdx.x * blockDim.x + threadIdx.x;
  if (i >= n4) return;
  float4 v = reinterpret_cast<const float4*>(in)[i];
  short4 o;
  o.x = f2bf(v.x); o.y = f2bf(v.y); o.z = f2bf(v.z); o.w = f2bf(v.w);
  reinterpret_cast<short4*>(out)[i] = o;
}

// ------------- transpose f32 [rows][cols] -> bf16 [cols][rows] -------------
__global__ void k_tr_w(const float* __restrict__ in, short* __restrict__ out,
                       int rows, int cols) {
  __shared__ float t[32][33];
  int c0 = blockIdx.x * 32, r0 = blockIdx.y * 32;
  int tx = threadIdx.x & 31, ty = threadIdx.x >> 5;
  #pragma unroll
  for (int i = ty; i < 32; i += 8) t[i][tx] = in[(size_t)(r0 + i) * cols + c0 + tx];
  __syncthreads();
  #pragma unroll
  for (int i = ty; i < 32; i += 8)
    out[(size_t)(c0 + i) * rows + r0 + tx] = f2bf(t[tx][i]);
}

// ------------- transpose V slice of qkv: per b, [T][1024] -> [1024][T] -------------
__global__ void k_tr_v(const short* __restrict__ qkv, short* __restrict__ vt) {
  __shared__ short t[32][33];
  int b = blockIdx.z;
  int t0 = blockIdx.x * 32, c0 = blockIdx.y * 32;
  int tx = threadIdx.x & 31, ty = threadIdx.x >> 5;
  #pragma unroll
  for (int i = ty; i < 32; i += 8)
    t[i][tx] = qkv[(size_t)(b * 2048 + t0 + i) * 3072 + 2048 + c0 + tx];
  __syncthreads();
  #pragma unroll
  for (int i = ty; i < 32; i += 8)
    vt[((size_t)(b * 1024 + c0 + i)) * 2048 + t0 + tx] = t[tx][i];
}

// ------------- bf16 GEMM: C[M][N] = A[M][K] * Bt[N][K]^T + bias -------------
// 128x128 tile, BK=32, 4 waves (2x2), 4x4 16x16 frags per wave.
// r8: double-buffered LDS with prefetch-before-compute (sync pattern proven in
// k_attn r6/r7): STAGE(t+1) -> ds_read+MFMA(t) -> ONE barrier (implicit vmcnt0
// drain lands after ~600cy of compute, not cold). Motivation: out-proj grid is
// 256 blocks = 1 block/CU -> no inter-block overlap; intra-block prefetch is
// the only latency hiding available there. QKV (3 blk/CU) expected ~flat
// (m99/m100: dbuf null when inter-block overlap exists). LDS 2x16K = 32 KiB.
template <int OUT_F32>
__global__ __launch_bounds__(256, 2)
void k_gemm_bt(const short* __restrict__ A, const short* __restrict__ Bt,
               const float* __restrict__ bias, void* __restrict__ Cout,
               int M, int N, int K, int qn, float qs) {
  __shared__ short As[2][128 * 32];
  __shared__ short Bs[2][128 * 32];
  const int tid = threadIdx.x;
  const int wid = tid >> 6, lane = tid & 63;
  const int g = lane >> 4, c = lane & 15;
  const int row0 = blockIdx.x * 128, col0 = blockIdx.y * 128;
  const int wr = wid >> 1, wc = wid & 1;
  f32x4 acc[4][4] = {};

  const int sR = lane >> 2;   // row within 16-row staging instr
  const int sp = lane & 3;    // physical chunk within 64B row

  auto STAGE = [&](int t) {
    int kt = t * 32;
    short* as = As[t & 1];
    short* bs = Bs[t & 1];
    #pragma unroll
    for (int i = 0; i < 2; ++i) {
      int R = wid * 32 + i * 16 + sR;
      int cc = sp ^ ((R >> 1) & 3);
      g2l16(A  + (size_t)(row0 + R) * K + kt + cc * 8, as + (wid * 32 + i * 16) * 32);
      g2l16(Bt + (size_t)(col0 + R) * K + kt + cc * 8, bs + (wid * 32 + i * 16) * 32);
    }
  };

  const int nt = K >> 5;
  STAGE(0);
  __syncthreads();

  for (int t = 0; t < nt; ++t) {
    if (t + 1 < nt) STAGE(t + 1);        // prefetch next K-tile into buf^1
    const short* as = As[t & 1];
    const short* bs = Bs[t & 1];
    bf16x8 af[4], bf[4];
    #pragma unroll
    for (int mi = 0; mi < 4; ++mi) {
      int r = wr * 64 + mi * 16 + c;
      int pc = g ^ ((r >> 1) & 3);
      af[mi] = *(const bf16x8*)&as[r * 32 + pc * 8];
    }
    #pragma unroll
    for (int ni = 0; ni < 4; ++ni) {
      int r = wc * 64 + ni * 16 + c;
      int pc = g ^ ((r >> 1) & 3);
      bf[ni] = *(const bf16x8*)&bs[r * 32 + pc * 8];
    }
    #pragma unroll
    for (int mi = 0; mi < 4; ++mi)
      #pragma unroll
      for (int ni = 0; ni < 4; ++ni)
        acc[mi][ni] = mfma16(af[mi], bf[ni], acc[mi][ni]);
    __syncthreads();   // reads of buf done + prefetch drained -> next iter safe
  }

  #pragma unroll
  for (int mi = 0; mi < 4; ++mi) {
    int r = row0 + wr * 64 + mi * 16 + g * 4;
    #pragma unroll
    for (int ni = 0; ni < 4; ++ni) {
      int cg = col0 + wc * 64 + ni * 16 + c;
      float bv = bias[cg];
      float sc = (cg < qn) ? qs : 1.0f;
      #pragma unroll
      for (int q = 0; q < 4; ++q) {
        float v = (acc[mi][ni][q] + bv) * sc;
        if (OUT_F32) ((float*)Cout)[(size_t)(r + q) * N + cg] = v;
        else         ((short*)Cout)[(size_t)(r + q) * N + cg] = f2bf(v);
      }
    }
  }
}

// ------------- causal flash attention (r7 structure, FROZEN: measured 51.0us) -------------
// Shell: 8-wave paired blocks (waves 0-3: q-tile p, 4-7: 15-p), shared K/V,
// double-buffered staging, balanced 2*(16-p) steps, 1 blk/CU.
// Inner: swapped QK^T (S^T = mfma(K,Q), q = lane&15), in-lane rowsum + 2 shfl,
// cvt_pk bf16 pack -> per-wave swizzled u32 LDS tile -> b128 A-frags,
// Q pre-scaled by 0.125*log2e in GEMM epilogue, boundary-only causal mask.
// r7 counters: 51.0us, MfmaUtil 12.3, VALUBusy 18.4, conflicts 1.08M (=0.003%
// of cycles, ignored). LDS 64K.
__global__ __launch_bounds__(512, 1)
void k_attn(const short* __restrict__ qkv, const short* __restrict__ vt,
            short* __restrict__ att) {
  constexpr int T = 2048, C3 = 3072, Cc = 1024;
  __shared__ short Ks[2][64 * 64];
  __shared__ short Vs[2][64 * 64];
  __shared__ unsigned int PbU[8][32 * 32];   // per-wave [q][kvp] u32 (2 bf16), swizzled
  const int tid = threadIdx.x, wid = tid >> 6, lane = tid & 63;
  const int g = lane >> 4, c = lane & 15;
  const int bh = blockIdx.y, b = bh >> 4, h = bh & 15;
  const int p = blockIdx.x;            // pair 0..7 (p=0 heaviest: 32 steps)
  const int grp = wid >> 2;            // 0: qt=p, 1: qt=15-p
  const int wl = wid & 3;              // wave position within its q-tile
  const int qt = grp ? (15 - p) : p;
  const int q0 = qt * 128;
  const int qrow = q0 + wl * 32;
  const int nsteps = 2 * (16 - p);

  // Q fragments (pre-scaled by 0.125*log2e in GEMM epilogue)
  bf16x8 qf[2][2];
  #pragma unroll
  for (int mi = 0; mi < 2; ++mi)
    #pragma unroll
    for (int kd = 0; kd < 2; ++kd)
      qf[mi][kd] = *(const bf16x8*)(qkv + (size_t)(b * T + qrow + mi * 16 + c) * C3
                                    + h * 64 + kd * 32 + g * 8);

  f32x4 oacc[2][4] = {};                // [mi_q16][nd_d16], C-layout row=q col=d
  float lsum[2] = {0.f, 0.f};           // per q = qrow + 16mi + c

  // staging: pre-swizzled global source, linear LDS dest
  const int sR = lane >> 3, sp = lane & 7;
  const int stR = wid * 8 + sR;
  const int scc = sp ^ (stR & 7);
  const short* ksrc = qkv + (size_t)b * T * C3 + Cc + h * 64 + scc * 8 + (size_t)stR * C3;
  const short* vsrc = vt + ((size_t)(b * Cc + h * 64 + stR)) * T + scc * 8;

  auto STAGE = [&](int t) {
    int kt = t * 64;
    int bufi = t & 1;
    g2l16(ksrc + (size_t)kt * C3, &Ks[bufi][(wid * 8) * 64]);
    g2l16(vsrc + kt,              &Vs[bufi][(wid * 8) * 64]);
  };

  STAGE(0);
  __syncthreads();

  unsigned int* pb = &PbU[wid][0];

  for (int t = 0; t < nsteps; ++t) {
    if (t + 1 < nsteps) STAGE(t + 1);
    const int kt = t * 64;
    const short* Kb = Ks[t & 1];
    const short* Vb = Vs[t & 1];

    if (kt <= qrow + 31) {   // wave-uniform causal skip
      // S^T = K Q^T : lane(g,c) reg r holds S[q=qrow+16mi+c][kv=kt+16ni+4g+r]
      f32x4 s[4][2] = {};
      #pragma unroll
      for (int kd = 0; kd < 2; ++kd) {
        #pragma unroll
        for (int ni = 0; ni < 4; ++ni) {
          int rr = ni * 16 + c;
          int pc = (kd * 4 + g) ^ (rr & 7);
          bf16x8 kf = *(const bf16x8*)&Kb[rr * 64 + pc * 8];
          #pragma unroll
          for (int mi = 0; mi < 2; ++mi)
            s[ni][mi] = mfma16(kf, qf[mi][kd], s[ni][mi]);
        }
      }
      // causal mask only on boundary steps (wave-uniform branch)
      if (kt + 63 > qrow) {
        #pragma unroll
        for (int ni = 0; ni < 4; ++ni)
          #pragma unroll
          for (int r = 0; r < 4; ++r) {
            int kg = kt + ni * 16 + g * 4 + r;
            #pragma unroll
            for (int mi = 0; mi < 2; ++mi) {
              int qg = qrow + mi * 16 + c;
              if (kg > qg) s[ni][mi][r] = -1000.0f;
            }
          }
      }
      // p = exp2(s)  (prescale folded upstream; constant factor cancels in p/sum)
      #pragma unroll
      for (int ni = 0; ni < 4; ++ni)
        #pragma unroll
        for (int mi = 0; mi < 2; ++mi)
          #pragma unroll
          for (int r = 0; r < 4; ++r)
            s[ni][mi][r] = EXP2(s[ni][mi][r]);
      // row sums: in-lane over (ni, r) + butterfly over g-lanes
      #pragma unroll
      for (int mi = 0; mi < 2; ++mi) {
        float rs = 0.f;
        #pragma unroll
        for (int ni = 0; ni < 4; ++ni)
          rs += (s[ni][mi][0] + s[ni][mi][1]) + (s[ni][mi][2] + s[ni][mi][3]);
        rs += __shfl_xor(rs, 16);
        rs += __shfl_xor(rs, 32);
        lsum[mi] += rs;
      }
      // pack P to bf16 pairs (HW RNE) and store to per-wave swizzled u32 tile.
      #pragma unroll
      for (int mi = 0; mi < 2; ++mi) {
        int q = mi * 16 + c;
        int rowb = q * 32;
        int sw = q & 7;
        #pragma unroll
        for (int ni = 0; ni < 4; ++ni) {
          unsigned int p0, p1;
          asm("v_cvt_pk_bf16_f32 %0, %1, %2"
              : "=v"(p0) : "v"(s[ni][mi][0]), "v"(s[ni][mi][1]));
          asm("v_cvt_pk_bf16_f32 %0, %1, %2"
              : "=v"(p1) : "v"(s[ni][mi][2]), "v"(s[ni][mi][3]));
          int idx = rowb + ((2 * ni + (g >> 1)) ^ sw) * 4 + 2 * (g & 1);
          uint2 w2; w2.x = p0; w2.y = p1;
          *reinterpret_cast<uint2*>(&pb[idx]) = w2;   // ds_write_b64
        }
      }
      // O += P V : A-frag = b128 read of PbU row q at chunk (4kk+g)^sw
      #pragma unroll
      for (int kk = 0; kk < 2; ++kk) {
        bf16x8 vf[4];
        #pragma unroll
        for (int nd = 0; nd < 4; ++nd) {
          int rr = nd * 16 + c;
          int pc = (kk * 4 + g) ^ (rr & 7);
          vf[nd] = *(const bf16x8*)&Vb[rr * 64 + pc * 8];
        }
        #pragma unroll
        for (int mi = 0; mi < 2; ++mi) {
          int q = mi * 16 + c;
          bf16x8 pa = *(const bf16x8*)&pb[q * 32 + ((4 * kk + g) ^ (q & 7)) * 4];
          #pragma unroll
          for (int nd = 0; nd < 4; ++nd)
            oacc[mi][nd] = mfma16(pa, vf[nd], oacc[mi][nd]);
        }
      }
    }
    __syncthreads();
  }

  // redistribute lsum (held by c-lanes) to output rows (g*4+r lanes) via LDS
  float* Lw = reinterpret_cast<float*>(pb);   // per-wave alias of dead PbU
  if (g == 0) { Lw[c] = lsum[0]; Lw[16 + c] = lsum[1]; }
  f32x4 l0 = *reinterpret_cast<const f32x4*>(&Lw[g * 4]);
  f32x4 l1 = *reinterpret_cast<const f32x4*>(&Lw[16 + g * 4]);
  f32x4 inv[2];
  #pragma unroll
  for (int r = 0; r < 4; ++r) { inv[0][r] = 1.0f / l0[r]; inv[1][r] = 1.0f / l1[r]; }

  #pragma unroll
  for (int mi = 0; mi < 2; ++mi)
    #pragma unroll
    for (int nd = 0; nd < 4; ++nd)
      #pragma unroll
      for (int r = 0; r < 4; ++r) {
        int qg = qrow + mi * 16 + g * 4 + r;
        att[(size_t)(b * T + qg) * Cc + h * 64 + nd * 16 + c] =
            f2bf(oacc[mi][nd][r] * inv[mi][r]);
      }
}

extern "C" void kernel_launch(void* const* d_in, const int* in_sizes, int n_in,
                              void* d_out, int out_size, void* d_ws, size_t ws_size,
                              hipStream_t stream) {
  (void)in_sizes; (void)n_in; (void)out_size; (void)ws_size;
  const float* x  = (const float*)d_in[0];
  const float* Wa = (const float*)d_in[1];
  const float* ba = (const float*)d_in[2];
  const float* Wo = (const float*)d_in[3];
  const float* bo = (const float*)d_in[4];
  float* out = (float*)d_out;

  // ws layout (bf16 buffers), total 48 MiB; att aliases dead xb.
  short* xb  = (short*)d_ws;                    // [4096][1024]  (later: att)
  short* Wat = xb  + (size_t)4096 * 1024;       // [3072][1024]
  short* Wot = Wat + (size_t)3072 * 1024;       // [1024][1024]
  short* qkv = Wot + (size_t)1024 * 1024;       // [4096][3072]
  short* vtb = qkv + (size_t)4096 * 3072;       // [2][1024][2048]
  short* att = xb;                              // alias: [4096][1024]

  const float QS = 0.125f * 1.44269504f;        // fold scale*log2e into Q cols

  k_cvt<<<4096, 256, 0, stream>>>(x, xb, 4096 * 1024 / 4);
  k_tr_w<<<dim3(96, 32), 256, 0, stream>>>(Wa, Wat, 1024, 3072);
  k_tr_w<<<dim3(32, 32), 256, 0, stream>>>(Wo, Wot, 1024, 1024);
  k_gemm_bt<0><<<dim3(32, 24), 256, 0, stream>>>(xb, Wat, ba, qkv, 4096, 3072, 1024,
                                                 1024, QS);
  k_tr_v<<<dim3(64, 32, 2), 256, 0, stream>>>(qkv, vtb);
  k_attn<<<dim3(8, 32), 512, 0, stream>>>(qkv, vtb, att);
  k_gemm_bt<1><<<dim3(32, 8), 256, 0, stream>>>(att, Wot, bo, out, 4096, 1024, 1024,
                                                0, 1.0f);
}